// Round 2
// baseline (2157.412 us; speedup 1.0000x reference)
//
#include <hip/hip_runtime.h>
#include <hip/hip_bf16.h>

#define N_NODES 100000
#define N_EDGES 1600000
#define N_GRAPHS 512
#define BN_EPS 1e-5f

__device__ __forceinline__ float bf2f(unsigned short u) {
    union { unsigned int i; float f; } c;
    c.i = ((unsigned int)u) << 16;
    return c.f;
}
__device__ __forceinline__ unsigned short f2bf(float f) {
    // round-to-nearest-even fp32 -> bf16
    union { float f; unsigned int i; } c; c.f = f;
    unsigned int lsb = (c.i >> 16) & 1;
    unsigned int r = c.i + 0x7FFFu + lsb;
    return (unsigned short)(r >> 16);
}

// h = x (copy); agg = 0   (vectorized float4)
__global__ void convert_zero_kernel(const float4* __restrict__ x,
                                    float4* __restrict__ h,
                                    float4* __restrict__ agg, int n4) {
    int i = blockIdx.x * blockDim.x + threadIdx.x;
    if (i < n4) {
        h[i] = x[i];
        agg[i] = make_float4(0.f, 0.f, 0.f, 0.f);
    }
}

// one wave (64 lanes) per edge: lane j adds h[src][j] into agg[dst][j]
__global__ void scatter_kernel(const float* __restrict__ h,
                               float* __restrict__ agg,
                               const int* __restrict__ ei) {
    int tid = blockIdx.x * blockDim.x + threadIdx.x;
    int e = tid >> 6;
    int j = tid & 63;
    if (e < N_EDGES) {
        int s = ei[e];
        int d = ei[N_EDGES + e];
        // defensive clamp: dtype surprises show up as finite absmax, not faults
        s = s < 0 ? 0 : (s >= N_NODES ? N_NODES - 1 : s);
        d = d < 0 ? 0 : (d >= N_NODES ? N_NODES - 1 : d);
        atomicAdd(&agg[(size_t)d * 64 + j], h[(size_t)s * 64 + j]);
    }
}

// Per-node fused MLP: z = h + agg; t = relu(BN1(z@W1+b1)); h = BN2(t@W2+b2) [,relu]
// BN folded: s1 into w1t rows; (b1-m1)*s1+bt1 as o1; s2/o2 applied at the end.
// Also re-zeroes agg for the next layer's scatter.
__launch_bounds__(256)
__global__ void mlp_kernel(float* __restrict__ h, float* __restrict__ agg,
                           const float* __restrict__ W1,   // [64][128]
                           const float* __restrict__ b1,
                           const float* __restrict__ g1,
                           const float* __restrict__ bt1,
                           const float* __restrict__ m1,
                           const float* __restrict__ v1,
                           const float* __restrict__ W2,   // [128][64]
                           const float* __restrict__ b2,
                           const float* __restrict__ g2,
                           const float* __restrict__ bt2,
                           const float* __restrict__ m2,
                           const float* __restrict__ v2,
                           int relu_out) {
    __shared__ float w1t[128 * 64];            // [jh][k] = W1[k][jh] * s1[jh]  (32 KB)
    __shared__ unsigned short w2s[128 * 64];   // bf16 of W2[jh][jo]            (16 KB)
    __shared__ float s1[128], o1[128], s2[64], o2[64];

    const int tid = threadIdx.x;

    // phase 1: BN fold params
    if (tid < 128) {
        float sv = g1[tid] * rsqrtf(v1[tid] + BN_EPS);
        s1[tid] = sv;
        o1[tid] = (b1[tid] - m1[tid]) * sv + bt1[tid];
    } else if (tid < 192) {
        int j = tid - 128;
        float sv = g2[j] * rsqrtf(v2[j] + BN_EPS);
        s2[j] = sv;
        o2[j] = (b2[j] - m2[j]) * sv + bt2[j];
    }
    __syncthreads();

    // phase 2: stage weights
    for (int idx = tid; idx < 64 * 128; idx += 256) {
        int k = idx >> 7;          // 0..63
        int jh = idx & 127;        // 0..127
        w1t[jh * 64 + k] = W1[idx] * s1[jh];   // W1[k][jh]
        w2s[idx] = f2bf(W2[idx]);              // W2[jh][jo]
    }
    __syncthreads();

    int n = blockIdx.x * blockDim.x + tid;
    if (n >= N_NODES) return;

    const size_t base = (size_t)n * 64;
    float z[64];
    {
        const float4* hv = (const float4*)(h + base);
        const float4* av = (const float4*)(agg + base);
        float4* azv = (float4*)(agg + base);
        #pragma unroll
        for (int k4 = 0; k4 < 16; ++k4) {
            float4 a = hv[k4];
            float4 b = av[k4];
            z[4 * k4 + 0] = a.x + b.x;
            z[4 * k4 + 1] = a.y + b.y;
            z[4 * k4 + 2] = a.z + b.z;
            z[4 * k4 + 3] = a.w + b.w;
            azv[k4] = make_float4(0.f, 0.f, 0.f, 0.f);   // re-zero agg for next layer
        }
    }

    float acc[64];
    #pragma unroll
    for (int jo = 0; jo < 64; ++jo) acc[jo] = 0.0f;

    for (int jh = 0; jh < 128; ++jh) {
        float t = 0.0f;
        const float4* wr = (const float4*)(&w1t[jh * 64]);
        #pragma unroll
        for (int k4 = 0; k4 < 16; ++k4) {
            float4 w = wr[k4];
            t += z[4 * k4 + 0] * w.x + z[4 * k4 + 1] * w.y
               + z[4 * k4 + 2] * w.z + z[4 * k4 + 3] * w.w;
        }
        t = t + o1[jh];            // s1 already folded into w1t
        t = fmaxf(t, 0.0f);

        const ushort4* w2r = (const ushort4*)(&w2s[jh * 64]);
        #pragma unroll
        for (int p = 0; p < 16; ++p) {
            ushort4 w = w2r[p];
            acc[4 * p + 0] += t * bf2f(w.x);
            acc[4 * p + 1] += t * bf2f(w.y);
            acc[4 * p + 2] += t * bf2f(w.z);
            acc[4 * p + 3] += t * bf2f(w.w);
        }
    }

    float4* hv = (float4*)(h + base);
    #pragma unroll
    for (int p = 0; p < 16; ++p) {
        float4 r;
        r.x = acc[4 * p + 0] * s2[4 * p + 0] + o2[4 * p + 0];
        r.y = acc[4 * p + 1] * s2[4 * p + 1] + o2[4 * p + 1];
        r.z = acc[4 * p + 2] * s2[4 * p + 2] + o2[4 * p + 2];
        r.w = acc[4 * p + 3] * s2[4 * p + 3] + o2[4 * p + 3];
        if (relu_out) {
            r.x = fmaxf(r.x, 0.f); r.y = fmaxf(r.y, 0.f);
            r.z = fmaxf(r.z, 0.f); r.w = fmaxf(r.w, 0.f);
        }
        hv[p] = r;
    }
}

// one block (64 threads) per graph; batch is sorted -> binary search boundaries
__global__ void pool_kernel(const float* __restrict__ h,
                            const int* __restrict__ batch,
                            float* __restrict__ out) {
    int g = blockIdx.x;
    int j = threadIdx.x;

    int lo = 0, hi = N_NODES;
    while (lo < hi) { int mid = (lo + hi) >> 1; if (batch[mid] < g) lo = mid + 1; else hi = mid; }
    int start = lo;
    hi = N_NODES;
    while (lo < hi) { int mid = (lo + hi) >> 1; if (batch[mid] < g + 1) lo = mid + 1; else hi = mid; }
    int end = lo;

    float sum = 0.0f;
    for (int n = start; n < end; ++n) sum += h[(size_t)n * 64 + j];
    float cnt = (float)(end - start);
    out[g * 64 + j] = sum / fmaxf(cnt, 1.0f);
}

extern "C" void kernel_launch(void* const* d_in, const int* in_sizes, int n_in,
                              void* d_out, int out_size, void* d_ws, size_t ws_size,
                              hipStream_t stream) {
    const float* x   = (const float*)d_in[0];
    const int* ei    = (const int*)d_in[1];
    const int* batch = (const int*)d_in[2];
    const float* W1  = (const float*)d_in[3];
    const float* b1  = (const float*)d_in[4];
    const float* g1  = (const float*)d_in[5];
    const float* bt1 = (const float*)d_in[6];
    const float* m1  = (const float*)d_in[7];
    const float* v1  = (const float*)d_in[8];
    const float* W2  = (const float*)d_in[9];
    const float* b2  = (const float*)d_in[10];
    const float* g2  = (const float*)d_in[11];
    const float* bt2 = (const float*)d_in[12];
    const float* m2  = (const float*)d_in[13];
    const float* v2  = (const float*)d_in[14];

    float* h   = (float*)d_ws;
    float* agg = h + (size_t)N_NODES * 64;

    float* out = (float*)d_out;

    const int n4 = N_NODES * 64 / 4;
    convert_zero_kernel<<<(n4 + 255) / 256, 256, 0, stream>>>(
        (const float4*)x, (float4*)h, (float4*)agg, n4);

    for (int l = 0; l < 4; ++l) {
        scatter_kernel<<<(N_EDGES * 64 + 255) / 256, 256, 0, stream>>>(h, agg, ei);
        mlp_kernel<<<(N_NODES + 255) / 256, 256, 0, stream>>>(
            h, agg,
            W1 + (size_t)l * 64 * 128, b1 + l * 128, g1 + l * 128, bt1 + l * 128,
            m1 + l * 128, v1 + l * 128,
            W2 + (size_t)l * 128 * 64, b2 + l * 64, g2 + l * 64, bt2 + l * 64,
            m2 + l * 64, v2 + l * 64,
            (l != 3) ? 1 : 0);
    }

    pool_kernel<<<N_GRAPHS, 64, 0, stream>>>(h, batch, out);
}

// Round 3
// 1193.609 us; speedup vs baseline: 1.8075x; 1.8075x over previous
//
#include <hip/hip_runtime.h>
#include <hip/hip_bf16.h>

#define N_NODES 100000
#define N_EDGES 1600000
#define N_GRAPHS 512
#define BN_EPS 1e-5f
#define NBLK_SCAN ((N_NODES + 255) / 256)   // 391

__device__ __forceinline__ float bf2f(unsigned short u) {
    union { unsigned int i; float f; } c;
    c.i = ((unsigned int)u) << 16;
    return c.f;
}
__device__ __forceinline__ unsigned short f2bf(float f) {
    union { float f; unsigned int i; } c; c.f = f;
    unsigned int lsb = (c.i >> 16) & 1;
    unsigned int r = c.i + 0x7FFFu + lsb;
    return (unsigned short)(r >> 16);
}
__device__ __forceinline__ int clampn(int v) {
    return v < 0 ? 0 : (v >= N_NODES ? N_NODES - 1 : v);
}

// ---------- CSR build ----------
__global__ void zero_int_kernel(int* __restrict__ p, int n) {
    int i = blockIdx.x * blockDim.x + threadIdx.x;
    if (i < n) p[i] = 0;
}

__global__ void hist_kernel(const int* __restrict__ ei, int* __restrict__ cnt) {
    int e = blockIdx.x * blockDim.x + threadIdx.x;
    if (e < N_EDGES) atomicAdd(&cnt[clampn(ei[N_EDGES + e])], 1);
}

// phase A: per-block (256-elem chunk) sums
__global__ void scanA_kernel(const int* __restrict__ cnt, int* __restrict__ bsum) {
    __shared__ int sc[256];
    int t = threadIdx.x;
    int idx = blockIdx.x * 256 + t;
    sc[t] = (idx < N_NODES) ? cnt[idx] : 0;
    __syncthreads();
    for (int off = 128; off > 0; off >>= 1) {
        if (t < off) sc[t] += sc[t + off];
        __syncthreads();
    }
    if (t == 0) bsum[blockIdx.x] = sc[0];
}

// phase B: single block, exclusive scan of block sums
__global__ void scanB_kernel(const int* __restrict__ bsum, int* __restrict__ boff) {
    __shared__ int sb[NBLK_SCAN];
    int t = threadIdx.x;
    for (int i = t; i < NBLK_SCAN; i += blockDim.x) sb[i] = bsum[i];
    __syncthreads();
    if (t == 0) {
        int run = 0;
        for (int i = 0; i < NBLK_SCAN; ++i) { int v = sb[i]; sb[i] = run; run += v; }
    }
    __syncthreads();
    for (int i = t; i < NBLK_SCAN; i += blockDim.x) boff[i] = sb[i];
}

// phase C: per-chunk exclusive scan + block offset -> row_start, cursor
__global__ void scanC_kernel(const int* __restrict__ cnt, const int* __restrict__ boff,
                             int* __restrict__ row_start, int* __restrict__ cursor) {
    __shared__ int sc[256];
    int t = threadIdx.x;
    int idx = blockIdx.x * 256 + t;
    int v = (idx < N_NODES) ? cnt[idx] : 0;
    sc[t] = v;
    __syncthreads();
    for (int off = 1; off < 256; off <<= 1) {
        int add = (t >= off) ? sc[t - off] : 0;
        __syncthreads();
        sc[t] += add;
        __syncthreads();
    }
    if (idx < N_NODES) {
        int rs = boff[blockIdx.x] + sc[t] - v;   // exclusive
        row_start[idx] = rs;
        cursor[idx] = rs;
    }
    if (idx == 0) row_start[N_NODES] = N_EDGES;  // all edges clamped in-range
}

__global__ void fill_kernel(const int* __restrict__ ei, int* __restrict__ cursor,
                            int* __restrict__ adj) {
    int e = blockIdx.x * blockDim.x + threadIdx.x;
    if (e < N_EDGES) {
        int s = clampn(ei[e]);
        int d = clampn(ei[N_EDGES + e]);
        int pos = atomicAdd(&cursor[d], 1);
        adj[pos] = s;
    }
}

// ---------- per-layer aggregation: one wave per node, lane = feature ----------
__global__ void gather_kernel(const float* __restrict__ hin, float* __restrict__ agg,
                              const int* __restrict__ row_start,
                              const int* __restrict__ adj) {
    int tid = blockIdx.x * blockDim.x + threadIdx.x;
    int n = tid >> 6;
    int j = tid & 63;
    if (n >= N_NODES) return;
    int beg = row_start[n];
    int end = row_start[n + 1];
    float sum = 0.0f;
    int i = beg;
    for (; i + 4 <= end; i += 4) {
        int s0 = adj[i], s1 = adj[i + 1], s2 = adj[i + 2], s3 = adj[i + 3];
        float a0 = hin[(size_t)s0 * 64 + j];
        float a1 = hin[(size_t)s1 * 64 + j];
        float a2 = hin[(size_t)s2 * 64 + j];
        float a3 = hin[(size_t)s3 * 64 + j];
        sum += a0 + a1 + a2 + a3;
    }
    for (; i < end; ++i) sum += hin[(size_t)adj[i] * 64 + j];
    agg[(size_t)n * 64 + j] = sum;
}

// ---------- per-node fused MLP (BN folded) ----------
__launch_bounds__(256)
__global__ void mlp_kernel(const float* __restrict__ hin, const float* __restrict__ agg,
                           float* __restrict__ hout,
                           const float* __restrict__ W1, const float* __restrict__ b1,
                           const float* __restrict__ g1, const float* __restrict__ bt1,
                           const float* __restrict__ m1, const float* __restrict__ v1,
                           const float* __restrict__ W2, const float* __restrict__ b2,
                           const float* __restrict__ g2, const float* __restrict__ bt2,
                           const float* __restrict__ m2, const float* __restrict__ v2,
                           int relu_out) {
    __shared__ float w1t[128 * 64];            // [jh][k] = W1[k][jh]*s1[jh]  (32 KB)
    __shared__ unsigned short w2s[128 * 64];   // bf16 of W2[jh][jo]          (16 KB)
    __shared__ float s1[128], o1[128], s2[64], o2[64];

    const int tid = threadIdx.x;

    if (tid < 128) {
        float sv = g1[tid] * rsqrtf(v1[tid] + BN_EPS);
        s1[tid] = sv;
        o1[tid] = (b1[tid] - m1[tid]) * sv + bt1[tid];
    } else if (tid < 192) {
        int j = tid - 128;
        float sv = g2[j] * rsqrtf(v2[j] + BN_EPS);
        s2[j] = sv;
        o2[j] = (b2[j] - m2[j]) * sv + bt2[j];
    }
    __syncthreads();

    for (int idx = tid; idx < 64 * 128; idx += 256) {
        int k = idx >> 7;
        int jh = idx & 127;
        w1t[jh * 64 + k] = W1[idx] * s1[jh];
        w2s[idx] = f2bf(W2[idx]);
    }
    __syncthreads();

    int n = blockIdx.x * blockDim.x + tid;
    if (n >= N_NODES) return;

    const size_t base = (size_t)n * 64;
    float z[64];
    {
        const float4* hv = (const float4*)(hin + base);
        const float4* av = (const float4*)(agg + base);
        #pragma unroll
        for (int k4 = 0; k4 < 16; ++k4) {
            float4 a = hv[k4];
            float4 b = av[k4];
            z[4 * k4 + 0] = a.x + b.x;
            z[4 * k4 + 1] = a.y + b.y;
            z[4 * k4 + 2] = a.z + b.z;
            z[4 * k4 + 3] = a.w + b.w;
        }
    }

    float acc[64];
    #pragma unroll
    for (int jo = 0; jo < 64; ++jo) acc[jo] = 0.0f;

    for (int jh = 0; jh < 128; ++jh) {
        float t = 0.0f;
        const float4* wr = (const float4*)(&w1t[jh * 64]);
        #pragma unroll
        for (int k4 = 0; k4 < 16; ++k4) {
            float4 w = wr[k4];
            t += z[4 * k4 + 0] * w.x + z[4 * k4 + 1] * w.y
               + z[4 * k4 + 2] * w.z + z[4 * k4 + 3] * w.w;
        }
        t = t + o1[jh];
        t = fmaxf(t, 0.0f);

        const ushort4* w2r = (const ushort4*)(&w2s[jh * 64]);
        #pragma unroll
        for (int p = 0; p < 16; ++p) {
            ushort4 w = w2r[p];
            acc[4 * p + 0] += t * bf2f(w.x);
            acc[4 * p + 1] += t * bf2f(w.y);
            acc[4 * p + 2] += t * bf2f(w.z);
            acc[4 * p + 3] += t * bf2f(w.w);
        }
    }

    float4* hv = (float4*)(hout + base);
    #pragma unroll
    for (int p = 0; p < 16; ++p) {
        float4 r;
        r.x = acc[4 * p + 0] * s2[4 * p + 0] + o2[4 * p + 0];
        r.y = acc[4 * p + 1] * s2[4 * p + 1] + o2[4 * p + 1];
        r.z = acc[4 * p + 2] * s2[4 * p + 2] + o2[4 * p + 2];
        r.w = acc[4 * p + 3] * s2[4 * p + 3] + o2[4 * p + 3];
        if (relu_out) {
            r.x = fmaxf(r.x, 0.f); r.y = fmaxf(r.y, 0.f);
            r.z = fmaxf(r.z, 0.f); r.w = fmaxf(r.w, 0.f);
        }
        hv[p] = r;
    }
}

// ---------- pool: one block per graph; batch sorted -> binary search ----------
__global__ void pool_kernel(const float* __restrict__ h,
                            const int* __restrict__ batch,
                            float* __restrict__ out) {
    int g = blockIdx.x;
    int j = threadIdx.x;

    int lo = 0, hi = N_NODES;
    while (lo < hi) { int mid = (lo + hi) >> 1; if (batch[mid] < g) lo = mid + 1; else hi = mid; }
    int start = lo;
    hi = N_NODES;
    while (lo < hi) { int mid = (lo + hi) >> 1; if (batch[mid] < g + 1) lo = mid + 1; else hi = mid; }
    int end = lo;

    float sum = 0.0f;
    for (int n = start; n < end; ++n) sum += h[(size_t)n * 64 + j];
    float cnt = (float)(end - start);
    out[g * 64 + j] = sum / fmaxf(cnt, 1.0f);
}

extern "C" void kernel_launch(void* const* d_in, const int* in_sizes, int n_in,
                              void* d_out, int out_size, void* d_ws, size_t ws_size,
                              hipStream_t stream) {
    const float* x   = (const float*)d_in[0];
    const int* ei    = (const int*)d_in[1];
    const int* batch = (const int*)d_in[2];
    const float* W1  = (const float*)d_in[3];
    const float* b1  = (const float*)d_in[4];
    const float* g1  = (const float*)d_in[5];
    const float* bt1 = (const float*)d_in[6];
    const float* m1  = (const float*)d_in[7];
    const float* v1  = (const float*)d_in[8];
    const float* W2  = (const float*)d_in[9];
    const float* b2  = (const float*)d_in[10];
    const float* g2  = (const float*)d_in[11];
    const float* bt2 = (const float*)d_in[12];
    const float* m2  = (const float*)d_in[13];
    const float* v2  = (const float*)d_in[14];

    // workspace layout
    float* h   = (float*)d_ws;                          // 25.6 MB
    float* agg = h + (size_t)N_NODES * 64;              // 25.6 MB
    int* iws       = (int*)(agg + (size_t)N_NODES * 64);
    int* cnt       = iws;                               // N
    int* row_start = cnt + N_NODES;                     // N+1
    int* cursor    = row_start + N_NODES + 1;           // N
    int* adj       = cursor + N_NODES;                  // E (6.4 MB)
    int* bsum      = adj + N_EDGES;                     // NBLK_SCAN
    int* boff      = bsum + NBLK_SCAN;                  // NBLK_SCAN

    float* out = (float*)d_out;

    const int EB = (N_EDGES + 255) / 256;

    // ---- CSR build (once per launch, reused by all 4 layers) ----
    zero_int_kernel<<<NBLK_SCAN, 256, 0, stream>>>(cnt, N_NODES);
    hist_kernel<<<EB, 256, 0, stream>>>(ei, cnt);
    scanA_kernel<<<NBLK_SCAN, 256, 0, stream>>>(cnt, bsum);
    scanB_kernel<<<1, 512, 0, stream>>>(bsum, boff);
    scanC_kernel<<<NBLK_SCAN, 256, 0, stream>>>(cnt, boff, row_start, cursor);
    fill_kernel<<<EB, 256, 0, stream>>>(ei, cursor, adj);

    // ---- 4 GIN layers ----
    const int GB = (N_NODES * 64 + 255) / 256;
    const int MB = (N_NODES + 255) / 256;
    for (int l = 0; l < 4; ++l) {
        const float* hin = (l == 0) ? x : h;
        gather_kernel<<<GB, 256, 0, stream>>>(hin, agg, row_start, adj);
        mlp_kernel<<<MB, 256, 0, stream>>>(
            hin, agg, h,
            W1 + (size_t)l * 64 * 128, b1 + l * 128, g1 + l * 128, bt1 + l * 128,
            m1 + l * 128, v1 + l * 128,
            W2 + (size_t)l * 128 * 64, b2 + l * 64, g2 + l * 64, bt2 + l * 64,
            m2 + l * 64, v2 + l * 64,
            (l != 3) ? 1 : 0);
    }

    pool_kernel<<<N_GRAPHS, 64, 0, stream>>>(h, batch, out);
}

// Round 4
// 722.412 us; speedup vs baseline: 2.9864x; 1.6523x over previous
//
#include <hip/hip_runtime.h>
#include <hip/hip_bf16.h>

#define N_NODES 100000
#define N_EDGES 1600000
#define N_GRAPHS 512
#define BN_EPS 1e-5f
#define NBLK_SCAN ((N_NODES + 255) / 256)   // 391
#define BM 128                               // nodes per block in MLP
#define NB_MLP ((N_NODES + BM - 1) / BM)     // 782

typedef short v8s __attribute__((ext_vector_type(8)));
typedef float v4f __attribute__((ext_vector_type(4)));

__device__ __forceinline__ unsigned short f2bf(float f) {
    union { float f; unsigned int i; } c; c.f = f;
    unsigned int lsb = (c.i >> 16) & 1;
    unsigned int r = c.i + 0x7FFFu + lsb;
    return (unsigned short)(r >> 16);
}
__device__ __forceinline__ int clampn(int v) {
    return v < 0 ? 0 : (v >= N_NODES ? N_NODES - 1 : v);
}

// ---------- CSR build ----------
__global__ void zero_int_kernel(int* __restrict__ p, int n) {
    int i = blockIdx.x * blockDim.x + threadIdx.x;
    if (i < n) p[i] = 0;
}

__global__ void hist_kernel(const int* __restrict__ ei, int* __restrict__ cnt) {
    int e = blockIdx.x * blockDim.x + threadIdx.x;
    if (e < N_EDGES) atomicAdd(&cnt[clampn(ei[N_EDGES + e])], 1);
}

__global__ void scanA_kernel(const int* __restrict__ cnt, int* __restrict__ bsum) {
    __shared__ int sc[256];
    int t = threadIdx.x;
    int idx = blockIdx.x * 256 + t;
    sc[t] = (idx < N_NODES) ? cnt[idx] : 0;
    __syncthreads();
    for (int off = 128; off > 0; off >>= 1) {
        if (t < off) sc[t] += sc[t + off];
        __syncthreads();
    }
    if (t == 0) bsum[blockIdx.x] = sc[0];
}

__global__ void scanB_kernel(const int* __restrict__ bsum, int* __restrict__ boff) {
    __shared__ int sb[NBLK_SCAN];
    int t = threadIdx.x;
    for (int i = t; i < NBLK_SCAN; i += blockDim.x) sb[i] = bsum[i];
    __syncthreads();
    if (t == 0) {
        int run = 0;
        for (int i = 0; i < NBLK_SCAN; ++i) { int v = sb[i]; sb[i] = run; run += v; }
    }
    __syncthreads();
    for (int i = t; i < NBLK_SCAN; i += blockDim.x) boff[i] = sb[i];
}

__global__ void scanC_kernel(const int* __restrict__ cnt, const int* __restrict__ boff,
                             int* __restrict__ row_start, int* __restrict__ cursor) {
    __shared__ int sc[256];
    int t = threadIdx.x;
    int idx = blockIdx.x * 256 + t;
    int v = (idx < N_NODES) ? cnt[idx] : 0;
    sc[t] = v;
    __syncthreads();
    for (int off = 1; off < 256; off <<= 1) {
        int add = (t >= off) ? sc[t - off] : 0;
        __syncthreads();
        sc[t] += add;
        __syncthreads();
    }
    if (idx < N_NODES) {
        int rs = boff[blockIdx.x] + sc[t] - v;
        row_start[idx] = rs;
        cursor[idx] = rs;
    }
    if (idx == 0) row_start[N_NODES] = N_EDGES;
}

__global__ void fill_kernel(const int* __restrict__ ei, int* __restrict__ cursor,
                            int* __restrict__ adj) {
    int e = blockIdx.x * blockDim.x + threadIdx.x;
    if (e < N_EDGES) {
        int s = clampn(ei[e]);
        int d = clampn(ei[N_EDGES + e]);
        int pos = atomicAdd(&cursor[d], 1);
        adj[pos] = s;
    }
}

// ---------- aggregation: one wave per node, lane = feature ----------
__global__ void gather_kernel(const float* __restrict__ hin, float* __restrict__ agg,
                              const int* __restrict__ row_start,
                              const int* __restrict__ adj) {
    int tid = blockIdx.x * blockDim.x + threadIdx.x;
    int n = tid >> 6;
    int j = tid & 63;
    if (n >= N_NODES) return;
    int beg = row_start[n];
    int end = row_start[n + 1];
    float sum = 0.0f;
    int i = beg;
    for (; i + 4 <= end; i += 4) {
        int s0 = adj[i], s1 = adj[i + 1], s2 = adj[i + 2], s3 = adj[i + 3];
        float a0 = hin[(size_t)s0 * 64 + j];
        float a1 = hin[(size_t)s1 * 64 + j];
        float a2 = hin[(size_t)s2 * 64 + j];
        float a3 = hin[(size_t)s3 * 64 + j];
        sum += a0 + a1 + a2 + a3;
    }
    for (; i < end; ++i) sum += hin[(size_t)adj[i] * 64 + j];
    agg[(size_t)n * 64 + j] = sum;
}

// ---------- MFMA MLP: 128 nodes/block, 4 waves, 2 row-tiles each ----------
// LDS map (bytes):
//   0     s1[128] f32 | 512 o1[128] f32 | 1024 o2[64] f32 | 1280 s2[64] f32
//   1536  z   bf16 [128][72]   (18432)          -- aliased by t after GEMM1
//   19968 w1t bf16 [128 n][72 k] (18432)        -- aliased by t after GEMM1
//   1536  t   bf16 [128][136]  (34816, alias)
//   38400 w2t bf16 [64 jo][136 jh] (17408)
// total 55808
__launch_bounds__(256)
__global__ void mlp_mfma_kernel(const float* __restrict__ hin, const float* __restrict__ agg,
                                float* __restrict__ hout,
                                const float* __restrict__ W1, const float* __restrict__ b1,
                                const float* __restrict__ g1, const float* __restrict__ bt1,
                                const float* __restrict__ m1, const float* __restrict__ v1,
                                const float* __restrict__ W2, const float* __restrict__ b2,
                                const float* __restrict__ g2, const float* __restrict__ bt2,
                                const float* __restrict__ m2, const float* __restrict__ v2,
                                int relu_out) {
    __shared__ __align__(16) char smem[55808];
    float* s1p = (float*)(smem);
    float* o1p = (float*)(smem + 512);
    float* o2p = (float*)(smem + 1024);
    float* s2p = (float*)(smem + 1280);
    short* zb  = (short*)(smem + 1536);
    short* w1b = (short*)(smem + 19968);
    short* tb  = (short*)(smem + 1536);    // alias of z+w1t
    short* w2b = (short*)(smem + 38400);

    const int tid = threadIdx.x;
    const int nbase = blockIdx.x * BM;

    // --- BN fold ---
    if (tid < 128) {
        float sv = g1[tid] * rsqrtf(v1[tid] + BN_EPS);
        s1p[tid] = sv;
        o1p[tid] = (b1[tid] - m1[tid]) * sv + bt1[tid];
    } else if (tid < 192) {
        int j = tid - 128;
        float sv = g2[j] * rsqrtf(v2[j] + BN_EPS);
        s2p[j] = sv;
        o2p[j] = (b2[j] - m2[j]) * sv + bt2[j];
    }
    __syncthreads();

    // --- stage w1t[n][k] = bf16(W1[k][n] * s1[n]) ---
    {
        int n = tid & 127;
        int kc = tid >> 7;                 // 0..1 -> k in [kc*32, kc*32+32)
        float sv = s1p[n];
        for (int k = kc * 32; k < kc * 32 + 32; k += 2) {
            float w0 = W1[k * 128 + n] * sv;
            float w1 = W1[(k + 1) * 128 + n] * sv;
            unsigned int u = (unsigned int)f2bf(w0) | ((unsigned int)f2bf(w1) << 16);
            *(unsigned int*)(w1b + n * 72 + k) = u;
        }
    }
    // --- stage w2t[jo][jh] = bf16(W2[jh][jo] * s2[jo]) ---
    {
        int jo = tid & 63;
        int c = tid >> 6;                  // 0..3 -> jh in [c*32, c*32+32)
        float sv = s2p[jo];
        for (int jh = c * 32; jh < c * 32 + 32; jh += 2) {
            float w0 = W2[jh * 64 + jo] * sv;
            float w1 = W2[(jh + 1) * 64 + jo] * sv;
            unsigned int u = (unsigned int)f2bf(w0) | ((unsigned int)f2bf(w1) << 16);
            *(unsigned int*)(w2b + jo * 136 + jh) = u;
        }
    }
    // --- stage z[row][k] = bf16(hin[row][k] + agg[row][k]) ---
    {
        int row = tid >> 1;
        int half = tid & 1;                // 32 floats each
        int rg = nbase + row;
        rg = rg < N_NODES ? rg : N_NODES - 1;
        const float4* hv = (const float4*)(hin + (size_t)rg * 64 + half * 32);
        const float4* av = (const float4*)(agg + (size_t)rg * 64 + half * 32);
        #pragma unroll
        for (int i = 0; i < 8; ++i) {
            float4 a = hv[i];
            float4 b = av[i];
            uint2 u;
            u.x = (unsigned int)f2bf(a.x + b.x) | ((unsigned int)f2bf(a.y + b.y) << 16);
            u.y = (unsigned int)f2bf(a.z + b.z) | ((unsigned int)f2bf(a.w + b.w) << 16);
            *(uint2*)(zb + row * 72 + half * 32 + i * 4) = u;
        }
    }
    __syncthreads();

    const int wave = tid >> 6;
    const int lane = tid & 63;
    const int lr = lane & 15;
    const int quad = lane >> 4;
    const int m0 = wave * 32;

    // --- GEMM1: [32 x 64] @ [64 x 128] per wave ---
    v4f acc1[2][8];
    #pragma unroll
    for (int rt = 0; rt < 2; ++rt)
        #pragma unroll
        for (int ct = 0; ct < 8; ++ct)
            acc1[rt][ct] = (v4f){0.f, 0.f, 0.f, 0.f};

    #pragma unroll
    for (int ks = 0; ks < 2; ++ks) {
        int kb = ks * 32 + quad * 8;
        v8s a0 = *(const v8s*)(zb + (m0 + lr) * 72 + kb);
        v8s a1 = *(const v8s*)(zb + (m0 + 16 + lr) * 72 + kb);
        #pragma unroll
        for (int ct = 0; ct < 8; ++ct) {
            v8s bF = *(const v8s*)(w1b + (ct * 16 + lr) * 72 + kb);
            acc1[0][ct] = __builtin_amdgcn_mfma_f32_16x16x32_bf16(a0, bF, acc1[0][ct], 0, 0, 0);
            acc1[1][ct] = __builtin_amdgcn_mfma_f32_16x16x32_bf16(a1, bF, acc1[1][ct], 0, 0, 0);
        }
    }

    __syncthreads();   // everyone done reading z/w1t before t overwrites them

    // --- BN1 + ReLU, write t (bf16, A-layout-friendly row-major) ---
    #pragma unroll
    for (int rt = 0; rt < 2; ++rt) {
        #pragma unroll
        for (int ct = 0; ct < 8; ++ct) {
            int col = ct * 16 + lr;
            float o1v = o1p[col];
            #pragma unroll
            for (int r = 0; r < 4; ++r) {
                float v = acc1[rt][ct][r] + o1v;
                v = fmaxf(v, 0.0f);
                int row = m0 + rt * 16 + quad * 4 + r;
                tb[row * 136 + col] = (short)f2bf(v);
            }
        }
    }
    // same-wave write->read: compiler inserts lgkmcnt wait; no barrier needed

    // --- GEMM2: [32 x 128] @ [128 x 64] per wave ---
    v4f acc2[2][4];
    #pragma unroll
    for (int rt = 0; rt < 2; ++rt)
        #pragma unroll
        for (int ct = 0; ct < 4; ++ct)
            acc2[rt][ct] = (v4f){0.f, 0.f, 0.f, 0.f};

    #pragma unroll
    for (int ks = 0; ks < 4; ++ks) {
        int kb = ks * 32 + quad * 8;
        v8s a0 = *(const v8s*)(tb + (m0 + lr) * 136 + kb);
        v8s a1 = *(const v8s*)(tb + (m0 + 16 + lr) * 136 + kb);
        #pragma unroll
        for (int ct = 0; ct < 4; ++ct) {
            v8s bF = *(const v8s*)(w2b + (ct * 16 + lr) * 136 + kb);
            acc2[0][ct] = __builtin_amdgcn_mfma_f32_16x16x32_bf16(a0, bF, acc2[0][ct], 0, 0, 0);
            acc2[1][ct] = __builtin_amdgcn_mfma_f32_16x16x32_bf16(a1, bF, acc2[1][ct], 0, 0, 0);
        }
    }

    // --- BN2 (+ReLU except last layer), store fp32 ---
    #pragma unroll
    for (int rt = 0; rt < 2; ++rt) {
        #pragma unroll
        for (int ct = 0; ct < 4; ++ct) {
            int col = ct * 16 + lr;
            float o2v = o2p[col];
            #pragma unroll
            for (int r = 0; r < 4; ++r) {
                int row = m0 + rt * 16 + quad * 4 + r;
                int n = nbase + row;
                if (n < N_NODES) {
                    float v = acc2[rt][ct][r] + o2v;
                    if (relu_out) v = fmaxf(v, 0.0f);
                    hout[(size_t)n * 64 + col] = v;
                }
            }
        }
    }
}

// ---------- pool ----------
__global__ void pool_kernel(const float* __restrict__ h,
                            const int* __restrict__ batch,
                            float* __restrict__ out) {
    int g = blockIdx.x;
    int j = threadIdx.x;

    int lo = 0, hi = N_NODES;
    while (lo < hi) { int mid = (lo + hi) >> 1; if (batch[mid] < g) lo = mid + 1; else hi = mid; }
    int start = lo;
    hi = N_NODES;
    while (lo < hi) { int mid = (lo + hi) >> 1; if (batch[mid] < g + 1) lo = mid + 1; else hi = mid; }
    int end = lo;

    float sum = 0.0f;
    for (int n = start; n < end; ++n) sum += h[(size_t)n * 64 + j];
    float cnt = (float)(end - start);
    out[g * 64 + j] = sum / fmaxf(cnt, 1.0f);
}

extern "C" void kernel_launch(void* const* d_in, const int* in_sizes, int n_in,
                              void* d_out, int out_size, void* d_ws, size_t ws_size,
                              hipStream_t stream) {
    const float* x   = (const float*)d_in[0];
    const int* ei    = (const int*)d_in[1];
    const int* batch = (const int*)d_in[2];
    const float* W1  = (const float*)d_in[3];
    const float* b1  = (const float*)d_in[4];
    const float* g1  = (const float*)d_in[5];
    const float* bt1 = (const float*)d_in[6];
    const float* m1  = (const float*)d_in[7];
    const float* v1  = (const float*)d_in[8];
    const float* W2  = (const float*)d_in[9];
    const float* b2  = (const float*)d_in[10];
    const float* g2  = (const float*)d_in[11];
    const float* bt2 = (const float*)d_in[12];
    const float* m2  = (const float*)d_in[13];
    const float* v2  = (const float*)d_in[14];

    float* h   = (float*)d_ws;                          // 25.6 MB
    float* agg = h + (size_t)N_NODES * 64;              // 25.6 MB
    int* cnt       = (int*)(agg + (size_t)N_NODES * 64);
    int* row_start = cnt + N_NODES;
    int* cursor    = row_start + N_NODES + 1;
    int* adj       = cursor + N_NODES;                  // 6.4 MB
    int* bsum      = adj + N_EDGES;
    int* boff      = bsum + NBLK_SCAN;

    float* out = (float*)d_out;

    const int EB = (N_EDGES + 255) / 256;

    zero_int_kernel<<<NBLK_SCAN, 256, 0, stream>>>(cnt, N_NODES);
    hist_kernel<<<EB, 256, 0, stream>>>(ei, cnt);
    scanA_kernel<<<NBLK_SCAN, 256, 0, stream>>>(cnt, bsum);
    scanB_kernel<<<1, 512, 0, stream>>>(bsum, boff);
    scanC_kernel<<<NBLK_SCAN, 256, 0, stream>>>(cnt, boff, row_start, cursor);
    fill_kernel<<<EB, 256, 0, stream>>>(ei, cursor, adj);

    const int GB = (N_NODES * 64 + 255) / 256;
    for (int l = 0; l < 4; ++l) {
        const float* hin = (l == 0) ? x : h;
        gather_kernel<<<GB, 256, 0, stream>>>(hin, agg, row_start, adj);
        mlp_mfma_kernel<<<NB_MLP, 256, 0, stream>>>(
            hin, agg, h,
            W1 + (size_t)l * 64 * 128, b1 + l * 128, g1 + l * 128, bt1 + l * 128,
            m1 + l * 128, v1 + l * 128,
            W2 + (size_t)l * 128 * 64, b2 + l * 64, g2 + l * 64, bt2 + l * 64,
            m2 + l * 64, v2 + l * 64,
            (l != 3) ? 1 : 0);
    }

    pool_kernel<<<N_GRAPHS, 64, 0, stream>>>(h, batch, out);
}

// Round 5
// 678.502 us; speedup vs baseline: 3.1797x; 1.0647x over previous
//
#include <hip/hip_runtime.h>
#include <hip/hip_bf16.h>

#define N_NODES 100000
#define N_EDGES 1600000
#define N_GRAPHS 512
#define BN_EPS 1e-5f
#define NBLK_SCAN ((N_NODES + 255) / 256)   // 391
#define BM 128                               // nodes per block in MLP
#define NB_MLP ((N_NODES + BM - 1) / BM)     // 782

typedef short v8s __attribute__((ext_vector_type(8)));
typedef float v4f __attribute__((ext_vector_type(4)));

__device__ __forceinline__ unsigned short f2bf(float f) {
    union { float f; unsigned int i; } c; c.f = f;
    unsigned int lsb = (c.i >> 16) & 1;
    unsigned int r = c.i + 0x7FFFu + lsb;
    return (unsigned short)(r >> 16);
}
__device__ __forceinline__ float bflo(unsigned int u) {
    union { unsigned int i; float f; } c; c.i = u << 16; return c.f;
}
__device__ __forceinline__ float bfhi(unsigned int u) {
    union { unsigned int i; float f; } c; c.i = u & 0xFFFF0000u; return c.f;
}
__device__ __forceinline__ unsigned int packbf(float a, float b) {
    return (unsigned int)f2bf(a) | ((unsigned int)f2bf(b) << 16);
}
__device__ __forceinline__ int clampn(int v) {
    return v < 0 ? 0 : (v >= N_NODES ? N_NODES - 1 : v);
}

// ---------- x fp32 -> bf16 ----------
__global__ void convert_kernel(const float4* __restrict__ x, uint2* __restrict__ xb, int n16) {
    int i = blockIdx.x * blockDim.x + threadIdx.x;
    if (i < n16) {
        float4 a = x[i];
        uint2 u;
        u.x = packbf(a.x, a.y);
        u.y = packbf(a.z, a.w);
        xb[i] = u;
    }
}

// ---------- CSR build ----------
__global__ void zero_int_kernel(int* __restrict__ p, int n) {
    int i = blockIdx.x * blockDim.x + threadIdx.x;
    if (i < n) p[i] = 0;
}

__global__ void hist_kernel(const int* __restrict__ ei, int* __restrict__ cnt) {
    int e = blockIdx.x * blockDim.x + threadIdx.x;
    if (e < N_EDGES) atomicAdd(&cnt[clampn(ei[N_EDGES + e])], 1);
}

__global__ void scanA_kernel(const int* __restrict__ cnt, int* __restrict__ bsum) {
    __shared__ int sc[256];
    int t = threadIdx.x;
    int idx = blockIdx.x * 256 + t;
    sc[t] = (idx < N_NODES) ? cnt[idx] : 0;
    __syncthreads();
    for (int off = 128; off > 0; off >>= 1) {
        if (t < off) sc[t] += sc[t + off];
        __syncthreads();
    }
    if (t == 0) bsum[blockIdx.x] = sc[0];
}

__global__ void scanB_kernel(const int* __restrict__ bsum, int* __restrict__ boff) {
    __shared__ int sb[NBLK_SCAN];
    int t = threadIdx.x;
    for (int i = t; i < NBLK_SCAN; i += blockDim.x) sb[i] = bsum[i];
    __syncthreads();
    if (t == 0) {
        int run = 0;
        for (int i = 0; i < NBLK_SCAN; ++i) { int v = sb[i]; sb[i] = run; run += v; }
    }
    __syncthreads();
    for (int i = t; i < NBLK_SCAN; i += blockDim.x) boff[i] = sb[i];
}

__global__ void scanC_kernel(const int* __restrict__ cnt, const int* __restrict__ boff,
                             int* __restrict__ row_start, int* __restrict__ cursor) {
    __shared__ int sc[256];
    int t = threadIdx.x;
    int idx = blockIdx.x * 256 + t;
    int v = (idx < N_NODES) ? cnt[idx] : 0;
    sc[t] = v;
    __syncthreads();
    for (int off = 1; off < 256; off <<= 1) {
        int add = (t >= off) ? sc[t - off] : 0;
        __syncthreads();
        sc[t] += add;
        __syncthreads();
    }
    if (idx < N_NODES) {
        int rs = boff[blockIdx.x] + sc[t] - v;
        row_start[idx] = rs;
        cursor[idx] = rs;
    }
    if (idx == 0) row_start[N_NODES] = N_EDGES;
}

__global__ void fill_kernel(const int* __restrict__ ei, int* __restrict__ cursor,
                            int* __restrict__ adj) {
    int e = blockIdx.x * blockDim.x + threadIdx.x;
    if (e < N_EDGES) {
        int s = clampn(ei[e]);
        int d = clampn(ei[N_EDGES + e]);
        int pos = atomicAdd(&cursor[d], 1);
        adj[pos] = s;
    }
}

// ---------- fused aggregation: z = bf16(h[n] + sum_{nbr} h[nbr]) ----------
// wave per node; 32 lanes x uint (2 bf16 features); half-waves take even/odd neighbors
__global__ void gather_kernel(const unsigned short* __restrict__ hin,
                              unsigned short* __restrict__ zb,
                              const int* __restrict__ row_start,
                              const int* __restrict__ adj) {
    int tid = blockIdx.x * blockDim.x + threadIdx.x;
    int n = tid >> 6;
    if (n >= N_NODES) return;
    int lane = tid & 63;
    int j2 = lane & 31;
    int par = lane >> 5;

    int beg = row_start[n];
    int end = row_start[n + 1];
    const unsigned int* hu = (const unsigned int*)hin;

    float s0 = 0.0f, s1 = 0.0f;
    int i = beg + par;
    for (; i + 2 < end; i += 4) {
        int a = adj[i], b = adj[i + 2];
        unsigned int ua = hu[(size_t)a * 32 + j2];
        unsigned int ub = hu[(size_t)b * 32 + j2];
        s0 += bflo(ua) + bflo(ub);
        s1 += bfhi(ua) + bfhi(ub);
    }
    if (i < end) {
        unsigned int ua = hu[(size_t)adj[i] * 32 + j2];
        s0 += bflo(ua);
        s1 += bfhi(ua);
    }
    s0 += __shfl_xor(s0, 32, 64);
    s1 += __shfl_xor(s1, 32, 64);

    if (par == 0) {
        unsigned int us = hu[(size_t)n * 32 + j2];
        float z0 = bflo(us) + s0;
        float z1 = bfhi(us) + s1;
        ((unsigned int*)zb)[(size_t)n * 32 + j2] = packbf(z0, z1);
    }
}

// ---------- MFMA MLP: 128 nodes/block, A-frags straight from global z ----------
// LDS: 0 s1[128] | 512 o1[128] | 1024 o2[64] | 1280 s2[64]
//      1536  t  bf16 [128][136] (34816, end 36352); w1 bf16 [128][72] aliases its head
//      36352 w2 bf16 [64][136]  (17408, end 53760)
__launch_bounds__(256)
__global__ void mlp_mfma_kernel(const unsigned short* __restrict__ zg,
                                unsigned short* __restrict__ hb,
                                const float* __restrict__ W1, const float* __restrict__ b1,
                                const float* __restrict__ g1, const float* __restrict__ bt1,
                                const float* __restrict__ m1, const float* __restrict__ v1,
                                const float* __restrict__ W2, const float* __restrict__ b2,
                                const float* __restrict__ g2, const float* __restrict__ bt2,
                                const float* __restrict__ m2, const float* __restrict__ v2,
                                int relu_out) {
    __shared__ __align__(16) char smem[53760];
    float* s1p = (float*)(smem);
    float* o1p = (float*)(smem + 512);
    float* o2p = (float*)(smem + 1024);
    float* s2p = (float*)(smem + 1280);
    short* tb  = (short*)(smem + 1536);
    short* w1b = (short*)(smem + 1536);    // alias: dead after GEMM1
    short* w2b = (short*)(smem + 36352);

    const int tid = threadIdx.x;
    const int nbase = blockIdx.x * BM;

    if (tid < 128) {
        float sv = g1[tid] * rsqrtf(v1[tid] + BN_EPS);
        s1p[tid] = sv;
        o1p[tid] = (b1[tid] - m1[tid]) * sv + bt1[tid];
    } else if (tid < 192) {
        int j = tid - 128;
        float sv = g2[j] * rsqrtf(v2[j] + BN_EPS);
        s2p[j] = sv;
        o2p[j] = (b2[j] - m2[j]) * sv + bt2[j];
    }
    __syncthreads();

    // stage w1t[n][k] = bf16(W1[k][n] * s1[n]), stride 72
    {
        int n = tid & 127;
        int kc = tid >> 7;
        float sv = s1p[n];
        for (int k = kc * 32; k < kc * 32 + 32; k += 2) {
            float w0 = W1[k * 128 + n] * sv;
            float w1 = W1[(k + 1) * 128 + n] * sv;
            unsigned int u = (unsigned int)f2bf(w0) | ((unsigned int)f2bf(w1) << 16);
            *(unsigned int*)(w1b + n * 72 + k) = u;
        }
    }
    // stage w2t[jo][jh] = bf16(W2[jh][jo] * s2[jo]), stride 136
    {
        int jo = tid & 63;
        int c = tid >> 6;
        float sv = s2p[jo];
        for (int jh = c * 32; jh < c * 32 + 32; jh += 2) {
            float w0 = W2[jh * 64 + jo] * sv;
            float w1 = W2[(jh + 1) * 64 + jo] * sv;
            unsigned int u = (unsigned int)f2bf(w0) | ((unsigned int)f2bf(w1) << 16);
            *(unsigned int*)(w2b + jo * 136 + jh) = u;
        }
    }
    __syncthreads();

    const int wave = tid >> 6;
    const int lane = tid & 63;
    const int lr = lane & 15;
    const int quad = lane >> 4;
    const int m0 = wave * 32;

    // A-fragments straight from global z (row-major bf16 rows of 64)
    int ra0 = nbase + m0 + lr;       ra0 = ra0 < N_NODES ? ra0 : N_NODES - 1;
    int ra1 = nbase + m0 + 16 + lr;  ra1 = ra1 < N_NODES ? ra1 : N_NODES - 1;
    const v8s* pa0 = (const v8s*)(zg + (size_t)ra0 * 64 + quad * 8);
    const v8s* pa1 = (const v8s*)(zg + (size_t)ra1 * 64 + quad * 8);
    v8s a0k[2], a1k[2];
    a0k[0] = pa0[0]; a0k[1] = pa0[4];   // k = quad*8, 32+quad*8
    a1k[0] = pa1[0]; a1k[1] = pa1[4];

    // GEMM1: [32 x 64] @ [64 x 128]
    v4f acc1[2][8];
    #pragma unroll
    for (int rt = 0; rt < 2; ++rt)
        #pragma unroll
        for (int ct = 0; ct < 8; ++ct)
            acc1[rt][ct] = (v4f){0.f, 0.f, 0.f, 0.f};

    #pragma unroll
    for (int ks = 0; ks < 2; ++ks) {
        int kb = ks * 32 + quad * 8;
        #pragma unroll
        for (int ct = 0; ct < 8; ++ct) {
            v8s bF = *(const v8s*)(w1b + (ct * 16 + lr) * 72 + kb);
            acc1[0][ct] = __builtin_amdgcn_mfma_f32_16x16x32_bf16(a0k[ks], bF, acc1[0][ct], 0, 0, 0);
            acc1[1][ct] = __builtin_amdgcn_mfma_f32_16x16x32_bf16(a1k[ks], bF, acc1[1][ct], 0, 0, 0);
        }
    }

    __syncthreads();   // all waves done reading w1b before t overwrites it

    // BN1 + ReLU -> t (bf16, [128][136])
    #pragma unroll
    for (int rt = 0; rt < 2; ++rt) {
        #pragma unroll
        for (int ct = 0; ct < 8; ++ct) {
            int col = ct * 16 + lr;
            float o1v = o1p[col];
            #pragma unroll
            for (int r = 0; r < 4; ++r) {
                float v = acc1[rt][ct][r] + o1v;
                v = fmaxf(v, 0.0f);
                int row = m0 + rt * 16 + quad * 4 + r;
                tb[row * 136 + col] = (short)f2bf(v);
            }
        }
    }
    // same-wave write->read on t rows: compiler inserts lgkmcnt wait

    // GEMM2: [32 x 128] @ [128 x 64]
    v4f acc2[2][4];
    #pragma unroll
    for (int rt = 0; rt < 2; ++rt)
        #pragma unroll
        for (int ct = 0; ct < 4; ++ct)
            acc2[rt][ct] = (v4f){0.f, 0.f, 0.f, 0.f};

    #pragma unroll
    for (int ks = 0; ks < 4; ++ks) {
        int kb = ks * 32 + quad * 8;
        v8s a0 = *(const v8s*)(tb + (m0 + lr) * 136 + kb);
        v8s a1 = *(const v8s*)(tb + (m0 + 16 + lr) * 136 + kb);
        #pragma unroll
        for (int ct = 0; ct < 4; ++ct) {
            v8s bF = *(const v8s*)(w2b + (ct * 16 + lr) * 136 + kb);
            acc2[0][ct] = __builtin_amdgcn_mfma_f32_16x16x32_bf16(a0, bF, acc2[0][ct], 0, 0, 0);
            acc2[1][ct] = __builtin_amdgcn_mfma_f32_16x16x32_bf16(a1, bF, acc2[1][ct], 0, 0, 0);
        }
    }

    // BN2 (+ReLU except last layer), store bf16 h
    #pragma unroll
    for (int rt = 0; rt < 2; ++rt) {
        #pragma unroll
        for (int ct = 0; ct < 4; ++ct) {
            int col = ct * 16 + lr;
            float o2v = o2p[col];
            #pragma unroll
            for (int r = 0; r < 4; ++r) {
                int row = m0 + rt * 16 + quad * 4 + r;
                int n = nbase + row;
                if (n < N_NODES) {
                    float v = acc2[rt][ct][r] + o2v;
                    if (relu_out) v = fmaxf(v, 0.0f);
                    hb[(size_t)n * 64 + col] = f2bf(v);
                }
            }
        }
    }
}

// ---------- pool: block per graph; 64 lanes read one 128B row per node ----------
__global__ void pool_kernel(const unsigned short* __restrict__ hb,
                            const int* __restrict__ batch,
                            float* __restrict__ out) {
    int g = blockIdx.x;
    int j = threadIdx.x;

    int lo = 0, hi = N_NODES;
    while (lo < hi) { int mid = (lo + hi) >> 1; if (batch[mid] < g) lo = mid + 1; else hi = mid; }
    int start = lo;
    hi = N_NODES;
    while (lo < hi) { int mid = (lo + hi) >> 1; if (batch[mid] < g + 1) lo = mid + 1; else hi = mid; }
    int end = lo;

    float sum = 0.0f;
    for (int n = start; n < end; ++n) {
        unsigned int u = (unsigned int)hb[(size_t)n * 64 + j];
        union { unsigned int i; float f; } c; c.i = u << 16;
        sum += c.f;
    }
    float cnt = (float)(end - start);
    out[g * 64 + j] = sum / fmaxf(cnt, 1.0f);
}

extern "C" void kernel_launch(void* const* d_in, const int* in_sizes, int n_in,
                              void* d_out, int out_size, void* d_ws, size_t ws_size,
                              hipStream_t stream) {
    const float* x   = (const float*)d_in[0];
    const int* ei    = (const int*)d_in[1];
    const int* batch = (const int*)d_in[2];
    const float* W1  = (const float*)d_in[3];
    const float* b1  = (const float*)d_in[4];
    const float* g1  = (const float*)d_in[5];
    const float* bt1 = (const float*)d_in[6];
    const float* m1  = (const float*)d_in[7];
    const float* v1  = (const float*)d_in[8];
    const float* W2  = (const float*)d_in[9];
    const float* b2  = (const float*)d_in[10];
    const float* g2  = (const float*)d_in[11];
    const float* bt2 = (const float*)d_in[12];
    const float* m2  = (const float*)d_in[13];
    const float* v2  = (const float*)d_in[14];

    // workspace
    unsigned short* hb = (unsigned short*)d_ws;              // 12.8 MB
    unsigned short* xb = hb + (size_t)N_NODES * 64;          // 12.8 MB
    unsigned short* zb = xb + (size_t)N_NODES * 64;          // 12.8 MB
    int* cnt       = (int*)(zb + (size_t)N_NODES * 64);
    int* row_start = cnt + N_NODES;
    int* cursor    = row_start + N_NODES + 1;
    int* adj       = cursor + N_NODES;                       // 6.4 MB
    int* bsum      = adj + N_EDGES;
    int* boff      = bsum + NBLK_SCAN;

    float* out = (float*)d_out;

    const int EB = (N_EDGES + 255) / 256;

    const int n16 = N_NODES * 16;
    convert_kernel<<<(n16 + 255) / 256, 256, 0, stream>>>((const float4*)x, (uint2*)xb, n16);

    zero_int_kernel<<<NBLK_SCAN, 256, 0, stream>>>(cnt, N_NODES);
    hist_kernel<<<EB, 256, 0, stream>>>(ei, cnt);
    scanA_kernel<<<NBLK_SCAN, 256, 0, stream>>>(cnt, bsum);
    scanB_kernel<<<1, 512, 0, stream>>>(bsum, boff);
    scanC_kernel<<<NBLK_SCAN, 256, 0, stream>>>(cnt, boff, row_start, cursor);
    fill_kernel<<<EB, 256, 0, stream>>>(ei, cursor, adj);

    const int GB = (N_NODES * 64 + 255) / 256;   // wave per node
    for (int l = 0; l < 4; ++l) {
        const unsigned short* hin = (l == 0) ? xb : hb;
        gather_kernel<<<GB, 256, 0, stream>>>(hin, zb, row_start, adj);
        mlp_mfma_kernel<<<NB_MLP, 256, 0, stream>>>(
            zb, hb,
            W1 + (size_t)l * 64 * 128, b1 + l * 128, g1 + l * 128, bt1 + l * 128,
            m1 + l * 128, v1 + l * 128,
            W2 + (size_t)l * 128 * 64, b2 + l * 64, g2 + l * 64, bt2 + l * 64,
            m2 + l * 64, v2 + l * 64,
            (l != 3) ? 1 : 0);
    }

    pool_kernel<<<N_GRAPHS, 64, 0, stream>>>(hb, batch, out);
}

// Round 6
// 674.818 us; speedup vs baseline: 3.1970x; 1.0055x over previous
//
#include <hip/hip_runtime.h>
#include <hip/hip_bf16.h>

#define N_NODES 100000
#define N_EDGES 1600000
#define N_GRAPHS 512
#define BN_EPS 1e-5f
#define NBLK_SCAN ((N_NODES + 255) / 256)   // 391
#define BM 128                               // nodes per block in MLP
#define NB_MLP ((N_NODES + BM - 1) / BM)     // 782

typedef short v8s __attribute__((ext_vector_type(8)));
typedef float v4f __attribute__((ext_vector_type(4)));

__device__ __forceinline__ unsigned short f2bf(float f) {
    union { float f; unsigned int i; } c; c.f = f;
    unsigned int lsb = (c.i >> 16) & 1;
    unsigned int r = c.i + 0x7FFFu + lsb;
    return (unsigned short)(r >> 16);
}
__device__ __forceinline__ float bflo(unsigned int u) {
    union { unsigned int i; float f; } c; c.i = u << 16; return c.f;
}
__device__ __forceinline__ float bfhi(unsigned int u) {
    union { unsigned int i; float f; } c; c.i = u & 0xFFFF0000u; return c.f;
}
__device__ __forceinline__ unsigned int packbf(float a, float b) {
    return (unsigned int)f2bf(a) | ((unsigned int)f2bf(b) << 16);
}
__device__ __forceinline__ int clampn(int v) {
    return v < 0 ? 0 : (v >= N_NODES ? N_NODES - 1 : v);
}

// ---------- x fp32 -> bf16 ----------
__global__ void convert_kernel(const float4* __restrict__ x, uint2* __restrict__ xb, int n16) {
    int i = blockIdx.x * blockDim.x + threadIdx.x;
    if (i < n16) {
        float4 a = x[i];
        uint2 u;
        u.x = packbf(a.x, a.y);
        u.y = packbf(a.z, a.w);
        xb[i] = u;
    }
}

// ---------- CSR build ----------
__global__ void zero_int_kernel(int* __restrict__ p, int n) {
    int i = blockIdx.x * blockDim.x + threadIdx.x;
    if (i < n) p[i] = 0;
}

__global__ void hist_kernel(const int* __restrict__ ei, int* __restrict__ cnt) {
    int e = blockIdx.x * blockDim.x + threadIdx.x;
    if (e < N_EDGES) atomicAdd(&cnt[clampn(ei[N_EDGES + e])], 1);
}

__global__ void scanA_kernel(const int* __restrict__ cnt, int* __restrict__ bsum) {
    __shared__ int sc[256];
    int t = threadIdx.x;
    int idx = blockIdx.x * 256 + t;
    sc[t] = (idx < N_NODES) ? cnt[idx] : 0;
    __syncthreads();
    for (int off = 128; off > 0; off >>= 1) {
        if (t < off) sc[t] += sc[t + off];
        __syncthreads();
    }
    if (t == 0) bsum[blockIdx.x] = sc[0];
}

__global__ void scanB_kernel(const int* __restrict__ bsum, int* __restrict__ boff) {
    __shared__ int sb[NBLK_SCAN];
    int t = threadIdx.x;
    for (int i = t; i < NBLK_SCAN; i += blockDim.x) sb[i] = bsum[i];
    __syncthreads();
    if (t == 0) {
        int run = 0;
        for (int i = 0; i < NBLK_SCAN; ++i) { int v = sb[i]; sb[i] = run; run += v; }
    }
    __syncthreads();
    for (int i = t; i < NBLK_SCAN; i += blockDim.x) boff[i] = sb[i];
}

__global__ void scanC_kernel(const int* __restrict__ cnt, const int* __restrict__ boff,
                             int* __restrict__ row_start, int* __restrict__ cursor) {
    __shared__ int sc[256];
    int t = threadIdx.x;
    int idx = blockIdx.x * 256 + t;
    int v = (idx < N_NODES) ? cnt[idx] : 0;
    sc[t] = v;
    __syncthreads();
    for (int off = 1; off < 256; off <<= 1) {
        int add = (t >= off) ? sc[t - off] : 0;
        __syncthreads();
        sc[t] += add;
        __syncthreads();
    }
    if (idx < N_NODES) {
        int rs = boff[blockIdx.x] + sc[t] - v;
        row_start[idx] = rs;
        cursor[idx] = rs;
    }
    if (idx == 0) row_start[N_NODES] = N_EDGES;
}

__global__ void fill_kernel(const int* __restrict__ ei, int* __restrict__ cursor,
                            int* __restrict__ adj) {
    int e = blockIdx.x * blockDim.x + threadIdx.x;
    if (e < N_EDGES) {
        int s = clampn(ei[e]);
        int d = clampn(ei[N_EDGES + e]);
        int pos = atomicAdd(&cursor[d], 1);
        adj[pos] = s;
    }
}

// ---------- fused aggregation: z = bf16(h[n] + sum_{nbr} h[nbr]) ----------
// wave per node; 32 lanes x uint (2 bf16 features); half-waves take even/odd neighbors.
// Deep-unrolled: 4 neighbor rows per half-wave in flight (8 rows/wave), index loads
// hoisted ahead of row loads to pipeline the index->row dependency chain.
__global__ void gather_kernel(const unsigned short* __restrict__ hin,
                              unsigned short* __restrict__ zb,
                              const int* __restrict__ row_start,
                              const int* __restrict__ adj) {
    int tid = blockIdx.x * blockDim.x + threadIdx.x;
    int n = tid >> 6;
    if (n >= N_NODES) return;
    int lane = tid & 63;
    int j2 = lane & 31;
    int par = lane >> 5;

    int beg = row_start[n];
    int end = row_start[n + 1];
    const unsigned int* hu = (const unsigned int*)hin;

    // issue self-row load early; only par==0 consumes it
    unsigned int us = 0;
    if (par == 0) us = hu[(size_t)n * 32 + j2];

    float s0 = 0.0f, s1 = 0.0f;
    int i = beg + par;

    // main loop: 4 neighbors per half-wave per iteration (positions i, i+2, i+4, i+6)
    for (; i + 6 < end; i += 8) {
        int a0 = adj[i];
        int a1 = adj[i + 2];
        int a2 = adj[i + 4];
        int a3 = adj[i + 6];
        unsigned int u0 = hu[(size_t)a0 * 32 + j2];
        unsigned int u1 = hu[(size_t)a1 * 32 + j2];
        unsigned int u2 = hu[(size_t)a2 * 32 + j2];
        unsigned int u3 = hu[(size_t)a3 * 32 + j2];
        s0 += (bflo(u0) + bflo(u1)) + (bflo(u2) + bflo(u3));
        s1 += (bfhi(u0) + bfhi(u1)) + (bfhi(u2) + bfhi(u3));
    }
    // tail: up to 3 neighbors per half-wave remain
    for (; i < end; i += 2) {
        unsigned int u = hu[(size_t)adj[i] * 32 + j2];
        s0 += bflo(u);
        s1 += bfhi(u);
    }

    s0 += __shfl_xor(s0, 32, 64);
    s1 += __shfl_xor(s1, 32, 64);

    if (par == 0) {
        float z0 = bflo(us) + s0;
        float z1 = bfhi(us) + s1;
        ((unsigned int*)zb)[(size_t)n * 32 + j2] = packbf(z0, z1);
    }
}

// ---------- MFMA MLP: 128 nodes/block, A-frags straight from global z ----------
// LDS: 0 s1[128] | 512 o1[128] | 1024 o2[64] | 1280 s2[64]
//      1536  t  bf16 [128][136] (34816, end 36352); w1 bf16 [128][72] aliases its head
//      36352 w2 bf16 [64][136]  (17408, end 53760)
__launch_bounds__(256)
__global__ void mlp_mfma_kernel(const unsigned short* __restrict__ zg,
                                unsigned short* __restrict__ hb,
                                const float* __restrict__ W1, const float* __restrict__ b1,
                                const float* __restrict__ g1, const float* __restrict__ bt1,
                                const float* __restrict__ m1, const float* __restrict__ v1,
                                const float* __restrict__ W2, const float* __restrict__ b2,
                                const float* __restrict__ g2, const float* __restrict__ bt2,
                                const float* __restrict__ m2, const float* __restrict__ v2,
                                int relu_out) {
    __shared__ __align__(16) char smem[53760];
    float* s1p = (float*)(smem);
    float* o1p = (float*)(smem + 512);
    float* o2p = (float*)(smem + 1024);
    float* s2p = (float*)(smem + 1280);
    short* tb  = (short*)(smem + 1536);
    short* w1b = (short*)(smem + 1536);    // alias: dead after GEMM1
    short* w2b = (short*)(smem + 36352);

    const int tid = threadIdx.x;
    const int nbase = blockIdx.x * BM;

    if (tid < 128) {
        float sv = g1[tid] * rsqrtf(v1[tid] + BN_EPS);
        s1p[tid] = sv;
        o1p[tid] = (b1[tid] - m1[tid]) * sv + bt1[tid];
    } else if (tid < 192) {
        int j = tid - 128;
        float sv = g2[j] * rsqrtf(v2[j] + BN_EPS);
        s2p[j] = sv;
        o2p[j] = (b2[j] - m2[j]) * sv + bt2[j];
    }
    __syncthreads();

    // stage w1t[n][k] = bf16(W1[k][n] * s1[n]), stride 72
    {
        int n = tid & 127;
        int kc = tid >> 7;
        float sv = s1p[n];
        for (int k = kc * 32; k < kc * 32 + 32; k += 2) {
            float w0 = W1[k * 128 + n] * sv;
            float w1 = W1[(k + 1) * 128 + n] * sv;
            unsigned int u = (unsigned int)f2bf(w0) | ((unsigned int)f2bf(w1) << 16);
            *(unsigned int*)(w1b + n * 72 + k) = u;
        }
    }
    // stage w2t[jo][jh] = bf16(W2[jh][jo] * s2[jo]), stride 136
    {
        int jo = tid & 63;
        int c = tid >> 6;
        float sv = s2p[jo];
        for (int jh = c * 32; jh < c * 32 + 32; jh += 2) {
            float w0 = W2[jh * 64 + jo] * sv;
            float w1 = W2[(jh + 1) * 64 + jo] * sv;
            unsigned int u = (unsigned int)f2bf(w0) | ((unsigned int)f2bf(w1) << 16);
            *(unsigned int*)(w2b + jo * 136 + jh) = u;
        }
    }
    __syncthreads();

    const int wave = tid >> 6;
    const int lane = tid & 63;
    const int lr = lane & 15;
    const int quad = lane >> 4;
    const int m0 = wave * 32;

    // A-fragments straight from global z (row-major bf16 rows of 64)
    int ra0 = nbase + m0 + lr;       ra0 = ra0 < N_NODES ? ra0 : N_NODES - 1;
    int ra1 = nbase + m0 + 16 + lr;  ra1 = ra1 < N_NODES ? ra1 : N_NODES - 1;
    const v8s* pa0 = (const v8s*)(zg + (size_t)ra0 * 64 + quad * 8);
    const v8s* pa1 = (const v8s*)(zg + (size_t)ra1 * 64 + quad * 8);
    v8s a0k[2], a1k[2];
    a0k[0] = pa0[0]; a0k[1] = pa0[4];   // k = quad*8, 32+quad*8
    a1k[0] = pa1[0]; a1k[1] = pa1[4];

    // GEMM1: [32 x 64] @ [64 x 128]
    v4f acc1[2][8];
    #pragma unroll
    for (int rt = 0; rt < 2; ++rt)
        #pragma unroll
        for (int ct = 0; ct < 8; ++ct)
            acc1[rt][ct] = (v4f){0.f, 0.f, 0.f, 0.f};

    #pragma unroll
    for (int ks = 0; ks < 2; ++ks) {
        int kb = ks * 32 + quad * 8;
        #pragma unroll
        for (int ct = 0; ct < 8; ++ct) {
            v8s bF = *(const v8s*)(w1b + (ct * 16 + lr) * 72 + kb);
            acc1[0][ct] = __builtin_amdgcn_mfma_f32_16x16x32_bf16(a0k[ks], bF, acc1[0][ct], 0, 0, 0);
            acc1[1][ct] = __builtin_amdgcn_mfma_f32_16x16x32_bf16(a1k[ks], bF, acc1[1][ct], 0, 0, 0);
        }
    }

    __syncthreads();   // all waves done reading w1b before t overwrites it

    // BN1 + ReLU -> t (bf16, [128][136])
    #pragma unroll
    for (int rt = 0; rt < 2; ++rt) {
        #pragma unroll
        for (int ct = 0; ct < 8; ++ct) {
            int col = ct * 16 + lr;
            float o1v = o1p[col];
            #pragma unroll
            for (int r = 0; r < 4; ++r) {
                float v = acc1[rt][ct][r] + o1v;
                v = fmaxf(v, 0.0f);
                int row = m0 + rt * 16 + quad * 4 + r;
                tb[row * 136 + col] = (short)f2bf(v);
            }
        }
    }
    // same-wave write->read on t rows: compiler inserts lgkmcnt wait

    // GEMM2: [32 x 128] @ [128 x 64]
    v4f acc2[2][4];
    #pragma unroll
    for (int rt = 0; rt < 2; ++rt)
        #pragma unroll
        for (int ct = 0; ct < 4; ++ct)
            acc2[rt][ct] = (v4f){0.f, 0.f, 0.f, 0.f};

    #pragma unroll
    for (int ks = 0; ks < 4; ++ks) {
        int kb = ks * 32 + quad * 8;
        v8s a0 = *(const v8s*)(tb + (m0 + lr) * 136 + kb);
        v8s a1 = *(const v8s*)(tb + (m0 + 16 + lr) * 136 + kb);
        #pragma unroll
        for (int ct = 0; ct < 4; ++ct) {
            v8s bF = *(const v8s*)(w2b + (ct * 16 + lr) * 136 + kb);
            acc2[0][ct] = __builtin_amdgcn_mfma_f32_16x16x32_bf16(a0, bF, acc2[0][ct], 0, 0, 0);
            acc2[1][ct] = __builtin_amdgcn_mfma_f32_16x16x32_bf16(a1, bF, acc2[1][ct], 0, 0, 0);
        }
    }

    // BN2 (+ReLU except last layer), store bf16 h
    #pragma unroll
    for (int rt = 0; rt < 2; ++rt) {
        #pragma unroll
        for (int ct = 0; ct < 4; ++ct) {
            int col = ct * 16 + lr;
            float o2v = o2p[col];
            #pragma unroll
            for (int r = 0; r < 4; ++r) {
                int row = m0 + rt * 16 + quad * 4 + r;
                int n = nbase + row;
                if (n < N_NODES) {
                    float v = acc2[rt][ct][r] + o2v;
                    if (relu_out) v = fmaxf(v, 0.0f);
                    hb[(size_t)n * 64 + col] = f2bf(v);
                }
            }
        }
    }
}

// ---------- pool: block per graph; 64 lanes read one 128B row per node ----------
__global__ void pool_kernel(const unsigned short* __restrict__ hb,
                            const int* __restrict__ batch,
                            float* __restrict__ out) {
    int g = blockIdx.x;
    int j = threadIdx.x;

    int lo = 0, hi = N_NODES;
    while (lo < hi) { int mid = (lo + hi) >> 1; if (batch[mid] < g) lo = mid + 1; else hi = mid; }
    int start = lo;
    hi = N_NODES;
    while (lo < hi) { int mid = (lo + hi) >> 1; if (batch[mid] < g + 1) lo = mid + 1; else hi = mid; }
    int end = lo;

    float sum = 0.0f;
    for (int n = start; n < end; ++n) {
        unsigned int u = (unsigned int)hb[(size_t)n * 64 + j];
        union { unsigned int i; float f; } c; c.i = u << 16;
        sum += c.f;
    }
    float cnt = (float)(end - start);
    out[g * 64 + j] = sum / fmaxf(cnt, 1.0f);
}

extern "C" void kernel_launch(void* const* d_in, const int* in_sizes, int n_in,
                              void* d_out, int out_size, void* d_ws, size_t ws_size,
                              hipStream_t stream) {
    const float* x   = (const float*)d_in[0];
    const int* ei    = (const int*)d_in[1];
    const int* batch = (const int*)d_in[2];
    const float* W1  = (const float*)d_in[3];
    const float* b1  = (const float*)d_in[4];
    const float* g1  = (const float*)d_in[5];
    const float* bt1 = (const float*)d_in[6];
    const float* m1  = (const float*)d_in[7];
    const float* v1  = (const float*)d_in[8];
    const float* W2  = (const float*)d_in[9];
    const float* b2  = (const float*)d_in[10];
    const float* g2  = (const float*)d_in[11];
    const float* bt2 = (const float*)d_in[12];
    const float* m2  = (const float*)d_in[13];
    const float* v2  = (const float*)d_in[14];

    // workspace
    unsigned short* hb = (unsigned short*)d_ws;              // 12.8 MB
    unsigned short* xb = hb + (size_t)N_NODES * 64;          // 12.8 MB
    unsigned short* zb = xb + (size_t)N_NODES * 64;          // 12.8 MB
    int* cnt       = (int*)(zb + (size_t)N_NODES * 64);
    int* row_start = cnt + N_NODES;
    int* cursor    = row_start + N_NODES + 1;
    int* adj       = cursor + N_NODES;                       // 6.4 MB
    int* bsum      = adj + N_EDGES;
    int* boff      = bsum + NBLK_SCAN;

    float* out = (float*)d_out;

    const int EB = (N_EDGES + 255) / 256;

    const int n16 = N_NODES * 16;
    convert_kernel<<<(n16 + 255) / 256, 256, 0, stream>>>((const float4*)x, (uint2*)xb, n16);

    zero_int_kernel<<<NBLK_SCAN, 256, 0, stream>>>(cnt, N_NODES);
    hist_kernel<<<EB, 256, 0, stream>>>(ei, cnt);
    scanA_kernel<<<NBLK_SCAN, 256, 0, stream>>>(cnt, bsum);
    scanB_kernel<<<1, 512, 0, stream>>>(bsum, boff);
    scanC_kernel<<<NBLK_SCAN, 256, 0, stream>>>(cnt, boff, row_start, cursor);
    fill_kernel<<<EB, 256, 0, stream>>>(ei, cursor, adj);

    const int GB = (N_NODES * 64 + 255) / 256;   // wave per node
    for (int l = 0; l < 4; ++l) {
        const unsigned short* hin = (l == 0) ? xb : hb;
        gather_kernel<<<GB, 256, 0, stream>>>(hin, zb, row_start, adj);
        mlp_mfma_kernel<<<NB_MLP, 256, 0, stream>>>(
            zb, hb,
            W1 + (size_t)l * 64 * 128, b1 + l * 128, g1 + l * 128, bt1 + l * 128,
            m1 + l * 128, v1 + l * 128,
            W2 + (size_t)l * 128 * 64, b2 + l * 64, g2 + l * 64, bt2 + l * 64,
            m2 + l * 64, v2 + l * 64,
            (l != 3) ? 1 : 0);
    }

    pool_kernel<<<N_GRAPHS, 64, 0, stream>>>(hb, batch, out);
}

// Round 7
// 631.664 us; speedup vs baseline: 3.4154x; 1.0683x over previous
//
#include <hip/hip_runtime.h>
#include <hip/hip_bf16.h>

#define N_NODES 100000
#define N_EDGES 1600000
#define N_GRAPHS 512
#define BN_EPS 1e-5f
#define NBLK_SCAN ((N_NODES + 255) / 256)   // 391
#define BM 128                               // nodes per block in MLP
#define NB_MLP ((N_NODES + BM - 1) / BM)     // 782

typedef short v8s __attribute__((ext_vector_type(8)));
typedef float v4f __attribute__((ext_vector_type(4)));

__device__ __forceinline__ unsigned short f2bf(float f) {
    union { float f; unsigned int i; } c; c.f = f;
    unsigned int lsb = (c.i >> 16) & 1;
    unsigned int r = c.i + 0x7FFFu + lsb;
    return (unsigned short)(r >> 16);
}
__device__ __forceinline__ float bflo(unsigned int u) {
    union { unsigned int i; float f; } c; c.i = u << 16; return c.f;
}
__device__ __forceinline__ float bfhi(unsigned int u) {
    union { unsigned int i; float f; } c; c.i = u & 0xFFFF0000u; return c.f;
}
__device__ __forceinline__ unsigned int packbf(float a, float b) {
    return (unsigned int)f2bf(a) | ((unsigned int)f2bf(b) << 16);
}
__device__ __forceinline__ int clampn(int v) {
    return v < 0 ? 0 : (v >= N_NODES ? N_NODES - 1 : v);
}

// ---------- x fp32 -> bf16 ----------
__global__ void convert_kernel(const float4* __restrict__ x, uint2* __restrict__ xb, int n16) {
    int i = blockIdx.x * blockDim.x + threadIdx.x;
    if (i < n16) {
        float4 a = x[i];
        uint2 u;
        u.x = packbf(a.x, a.y);
        u.y = packbf(a.z, a.w);
        xb[i] = u;
    }
}

// ---------- CSR build ----------
__global__ void zero_int_kernel(int* __restrict__ p, int n) {
    int i = blockIdx.x * blockDim.x + threadIdx.x;
    if (i < n) p[i] = 0;
}

__global__ void hist_kernel(const int* __restrict__ ei, int* __restrict__ cnt) {
    int e = blockIdx.x * blockDim.x + threadIdx.x;
    if (e < N_EDGES) atomicAdd(&cnt[clampn(ei[N_EDGES + e])], 1);
}

__global__ void scanA_kernel(const int* __restrict__ cnt, int* __restrict__ bsum) {
    __shared__ int sc[256];
    int t = threadIdx.x;
    int idx = blockIdx.x * 256 + t;
    sc[t] = (idx < N_NODES) ? cnt[idx] : 0;
    __syncthreads();
    for (int off = 128; off > 0; off >>= 1) {
        if (t < off) sc[t] += sc[t + off];
        __syncthreads();
    }
    if (t == 0) bsum[blockIdx.x] = sc[0];
}

__global__ void scanB_kernel(const int* __restrict__ bsum, int* __restrict__ boff) {
    __shared__ int sb[NBLK_SCAN];
    int t = threadIdx.x;
    for (int i = t; i < NBLK_SCAN; i += blockDim.x) sb[i] = bsum[i];
    __syncthreads();
    if (t == 0) {
        int run = 0;
        for (int i = 0; i < NBLK_SCAN; ++i) { int v = sb[i]; sb[i] = run; run += v; }
    }
    __syncthreads();
    for (int i = t; i < NBLK_SCAN; i += blockDim.x) boff[i] = sb[i];
}

__global__ void scanC_kernel(const int* __restrict__ cnt, const int* __restrict__ boff,
                             int* __restrict__ row_start, int* __restrict__ cursor) {
    __shared__ int sc[256];
    int t = threadIdx.x;
    int idx = blockIdx.x * 256 + t;
    int v = (idx < N_NODES) ? cnt[idx] : 0;
    sc[t] = v;
    __syncthreads();
    for (int off = 1; off < 256; off <<= 1) {
        int add = (t >= off) ? sc[t - off] : 0;
        __syncthreads();
        sc[t] += add;
        __syncthreads();
    }
    if (idx < N_NODES) {
        int rs = boff[blockIdx.x] + sc[t] - v;
        row_start[idx] = rs;
        cursor[idx] = rs;
    }
    if (idx == 0) row_start[N_NODES] = N_EDGES;
}

__global__ void fill_kernel(const int* __restrict__ ei, int* __restrict__ cursor,
                            int* __restrict__ adj) {
    int e = blockIdx.x * blockDim.x + threadIdx.x;
    if (e < N_EDGES) {
        int s = clampn(ei[e]);
        int d = clampn(ei[N_EDGES + e]);
        int pos = atomicAdd(&cursor[d], 1);
        adj[pos] = s;
    }
}

// ---------- fused aggregation: z = bf16(h[n] + sum_{nbr} h[nbr]) ----------
// Persistent: 1024 blocks x 256 thr = 8192 waves (device capacity). Half-wave (32
// lanes = one 128B bf16 row) owns a whole node; grid-stride over nodes. Neighbor
// walk in 8-deep independent load batches (8 idx then 8 rows) + 4/2/1 tail.
#define GATHER_BLOCKS 1024
__global__ void gather_kernel(const unsigned short* __restrict__ hin,
                              unsigned short* __restrict__ zb,
                              const int* __restrict__ row_start,
                              const int* __restrict__ adj) {
    const unsigned int* hu = (const unsigned int*)hin;
    unsigned int* zu = (unsigned int*)zb;
    const int j2 = threadIdx.x & 31;
    const int unit = (blockIdx.x * blockDim.x + threadIdx.x) >> 5;
    const int nunits = (gridDim.x * blockDim.x) >> 5;

    for (int n = unit; n < N_NODES; n += nunits) {
        int beg = row_start[n];
        int end = row_start[n + 1];
        unsigned int us = hu[(size_t)n * 32 + j2];   // self row
        float s0 = bflo(us), s1 = bfhi(us);

        int i = beg;
        for (; i + 8 <= end; i += 8) {
            int a0 = adj[i],     a1 = adj[i + 1], a2 = adj[i + 2], a3 = adj[i + 3];
            int a4 = adj[i + 4], a5 = adj[i + 5], a6 = adj[i + 6], a7 = adj[i + 7];
            unsigned int u0 = hu[(size_t)a0 * 32 + j2];
            unsigned int u1 = hu[(size_t)a1 * 32 + j2];
            unsigned int u2 = hu[(size_t)a2 * 32 + j2];
            unsigned int u3 = hu[(size_t)a3 * 32 + j2];
            unsigned int u4 = hu[(size_t)a4 * 32 + j2];
            unsigned int u5 = hu[(size_t)a5 * 32 + j2];
            unsigned int u6 = hu[(size_t)a6 * 32 + j2];
            unsigned int u7 = hu[(size_t)a7 * 32 + j2];
            s0 += ((bflo(u0) + bflo(u1)) + (bflo(u2) + bflo(u3)))
                + ((bflo(u4) + bflo(u5)) + (bflo(u6) + bflo(u7)));
            s1 += ((bfhi(u0) + bfhi(u1)) + (bfhi(u2) + bfhi(u3)))
                + ((bfhi(u4) + bfhi(u5)) + (bfhi(u6) + bfhi(u7)));
        }
        if (i + 4 <= end) {
            int a0 = adj[i], a1 = adj[i + 1], a2 = adj[i + 2], a3 = adj[i + 3];
            unsigned int u0 = hu[(size_t)a0 * 32 + j2];
            unsigned int u1 = hu[(size_t)a1 * 32 + j2];
            unsigned int u2 = hu[(size_t)a2 * 32 + j2];
            unsigned int u3 = hu[(size_t)a3 * 32 + j2];
            s0 += (bflo(u0) + bflo(u1)) + (bflo(u2) + bflo(u3));
            s1 += (bfhi(u0) + bfhi(u1)) + (bfhi(u2) + bfhi(u3));
            i += 4;
        }
        if (i + 2 <= end) {
            int a0 = adj[i], a1 = adj[i + 1];
            unsigned int u0 = hu[(size_t)a0 * 32 + j2];
            unsigned int u1 = hu[(size_t)a1 * 32 + j2];
            s0 += bflo(u0) + bflo(u1);
            s1 += bfhi(u0) + bfhi(u1);
            i += 2;
        }
        if (i < end) {
            unsigned int u0 = hu[(size_t)adj[i] * 32 + j2];
            s0 += bflo(u0);
            s1 += bfhi(u0);
        }

        zu[(size_t)n * 32 + j2] = packbf(s0, s1);
    }
}

// ---------- MFMA MLP: 128 nodes/block, A-frags straight from global z ----------
// LDS: 0 s1[128] | 512 o1[128] | 1024 o2[64] | 1280 s2[64]
//      1536  t  bf16 [128][136] (34816, end 36352); w1 bf16 [128][72] aliases its head
//      36352 w2 bf16 [64][136]  (17408, end 53760)
__launch_bounds__(256)
__global__ void mlp_mfma_kernel(const unsigned short* __restrict__ zg,
                                unsigned short* __restrict__ hb,
                                const float* __restrict__ W1, const float* __restrict__ b1,
                                const float* __restrict__ g1, const float* __restrict__ bt1,
                                const float* __restrict__ m1, const float* __restrict__ v1,
                                const float* __restrict__ W2, const float* __restrict__ b2,
                                const float* __restrict__ g2, const float* __restrict__ bt2,
                                const float* __restrict__ m2, const float* __restrict__ v2,
                                int relu_out) {
    __shared__ __align__(16) char smem[53760];
    float* s1p = (float*)(smem);
    float* o1p = (float*)(smem + 512);
    float* o2p = (float*)(smem + 1024);
    float* s2p = (float*)(smem + 1280);
    short* tb  = (short*)(smem + 1536);
    short* w1b = (short*)(smem + 1536);    // alias: dead after GEMM1
    short* w2b = (short*)(smem + 36352);

    const int tid = threadIdx.x;
    const int nbase = blockIdx.x * BM;

    if (tid < 128) {
        float sv = g1[tid] * rsqrtf(v1[tid] + BN_EPS);
        s1p[tid] = sv;
        o1p[tid] = (b1[tid] - m1[tid]) * sv + bt1[tid];
    } else if (tid < 192) {
        int j = tid - 128;
        float sv = g2[j] * rsqrtf(v2[j] + BN_EPS);
        s2p[j] = sv;
        o2p[j] = (b2[j] - m2[j]) * sv + bt2[j];
    }
    __syncthreads();

    // stage w1t[n][k] = bf16(W1[k][n] * s1[n]), stride 72
    {
        int n = tid & 127;
        int kc = tid >> 7;
        float sv = s1p[n];
        for (int k = kc * 32; k < kc * 32 + 32; k += 2) {
            float w0 = W1[k * 128 + n] * sv;
            float w1 = W1[(k + 1) * 128 + n] * sv;
            unsigned int u = (unsigned int)f2bf(w0) | ((unsigned int)f2bf(w1) << 16);
            *(unsigned int*)(w1b + n * 72 + k) = u;
        }
    }
    // stage w2t[jo][jh] = bf16(W2[jh][jo] * s2[jo]), stride 136
    {
        int jo = tid & 63;
        int c = tid >> 6;
        float sv = s2p[jo];
        for (int jh = c * 32; jh < c * 32 + 32; jh += 2) {
            float w0 = W2[jh * 64 + jo] * sv;
            float w1 = W2[(jh + 1) * 64 + jo] * sv;
            unsigned int u = (unsigned int)f2bf(w0) | ((unsigned int)f2bf(w1) << 16);
            *(unsigned int*)(w2b + jo * 136 + jh) = u;
        }
    }
    __syncthreads();

    const int wave = tid >> 6;
    const int lane = tid & 63;
    const int lr = lane & 15;
    const int quad = lane >> 4;
    const int m0 = wave * 32;

    // A-fragments straight from global z (row-major bf16 rows of 64)
    int ra0 = nbase + m0 + lr;       ra0 = ra0 < N_NODES ? ra0 : N_NODES - 1;
    int ra1 = nbase + m0 + 16 + lr;  ra1 = ra1 < N_NODES ? ra1 : N_NODES - 1;
    const v8s* pa0 = (const v8s*)(zg + (size_t)ra0 * 64 + quad * 8);
    const v8s* pa1 = (const v8s*)(zg + (size_t)ra1 * 64 + quad * 8);
    v8s a0k[2], a1k[2];
    a0k[0] = pa0[0]; a0k[1] = pa0[4];   // k = quad*8, 32+quad*8
    a1k[0] = pa1[0]; a1k[1] = pa1[4];

    // GEMM1: [32 x 64] @ [64 x 128]
    v4f acc1[2][8];
    #pragma unroll
    for (int rt = 0; rt < 2; ++rt)
        #pragma unroll
        for (int ct = 0; ct < 8; ++ct)
            acc1[rt][ct] = (v4f){0.f, 0.f, 0.f, 0.f};

    #pragma unroll
    for (int ks = 0; ks < 2; ++ks) {
        int kb = ks * 32 + quad * 8;
        #pragma unroll
        for (int ct = 0; ct < 8; ++ct) {
            v8s bF = *(const v8s*)(w1b + (ct * 16 + lr) * 72 + kb);
            acc1[0][ct] = __builtin_amdgcn_mfma_f32_16x16x32_bf16(a0k[ks], bF, acc1[0][ct], 0, 0, 0);
            acc1[1][ct] = __builtin_amdgcn_mfma_f32_16x16x32_bf16(a1k[ks], bF, acc1[1][ct], 0, 0, 0);
        }
    }

    __syncthreads();   // all waves done reading w1b before t overwrites it

    // BN1 + ReLU -> t (bf16, [128][136])
    #pragma unroll
    for (int rt = 0; rt < 2; ++rt) {
        #pragma unroll
        for (int ct = 0; ct < 8; ++ct) {
            int col = ct * 16 + lr;
            float o1v = o1p[col];
            #pragma unroll
            for (int r = 0; r < 4; ++r) {
                float v = acc1[rt][ct][r] + o1v;
                v = fmaxf(v, 0.0f);
                int row = m0 + rt * 16 + quad * 4 + r;
                tb[row * 136 + col] = (short)f2bf(v);
            }
        }
    }
    // same-wave write->read on t rows: compiler inserts lgkmcnt wait

    // GEMM2: [32 x 128] @ [128 x 64]
    v4f acc2[2][4];
    #pragma unroll
    for (int rt = 0; rt < 2; ++rt)
        #pragma unroll
        for (int ct = 0; ct < 4; ++ct)
            acc2[rt][ct] = (v4f){0.f, 0.f, 0.f, 0.f};

    #pragma unroll
    for (int ks = 0; ks < 4; ++ks) {
        int kb = ks * 32 + quad * 8;
        v8s a0 = *(const v8s*)(tb + (m0 + lr) * 136 + kb);
        v8s a1 = *(const v8s*)(tb + (m0 + 16 + lr) * 136 + kb);
        #pragma unroll
        for (int ct = 0; ct < 4; ++ct) {
            v8s bF = *(const v8s*)(w2b + (ct * 16 + lr) * 136 + kb);
            acc2[0][ct] = __builtin_amdgcn_mfma_f32_16x16x32_bf16(a0, bF, acc2[0][ct], 0, 0, 0);
            acc2[1][ct] = __builtin_amdgcn_mfma_f32_16x16x32_bf16(a1, bF, acc2[1][ct], 0, 0, 0);
        }
    }

    // BN2 (+ReLU except last layer), store bf16 h
    #pragma unroll
    for (int rt = 0; rt < 2; ++rt) {
        #pragma unroll
        for (int ct = 0; ct < 4; ++ct) {
            int col = ct * 16 + lr;
            float o2v = o2p[col];
            #pragma unroll
            for (int r = 0; r < 4; ++r) {
                int row = m0 + rt * 16 + quad * 4 + r;
                int n = nbase + row;
                if (n < N_NODES) {
                    float v = acc2[rt][ct][r] + o2v;
                    if (relu_out) v = fmaxf(v, 0.0f);
                    hb[(size_t)n * 64 + col] = f2bf(v);
                }
            }
        }
    }
}

// ---------- pool: block per graph; 64 lanes read one 128B row per node ----------
__global__ void pool_kernel(const unsigned short* __restrict__ hb,
                            const int* __restrict__ batch,
                            float* __restrict__ out) {
    int g = blockIdx.x;
    int j = threadIdx.x;

    int lo = 0, hi = N_NODES;
    while (lo < hi) { int mid = (lo + hi) >> 1; if (batch[mid] < g) lo = mid + 1; else hi = mid; }
    int start = lo;
    hi = N_NODES;
    while (lo < hi) { int mid = (lo + hi) >> 1; if (batch[mid] < g + 1) lo = mid + 1; else hi = mid; }
    int end = lo;

    float sum = 0.0f;
    for (int n = start; n < end; ++n) {
        unsigned int u = (unsigned int)hb[(size_t)n * 64 + j];
        union { unsigned int i; float f; } c; c.i = u << 16;
        sum += c.f;
    }
    float cnt = (float)(end - start);
    out[g * 64 + j] = sum / fmaxf(cnt, 1.0f);
}

extern "C" void kernel_launch(void* const* d_in, const int* in_sizes, int n_in,
                              void* d_out, int out_size, void* d_ws, size_t ws_size,
                              hipStream_t stream) {
    const float* x   = (const float*)d_in[0];
    const int* ei    = (const int*)d_in[1];
    const int* batch = (const int*)d_in[2];
    const float* W1  = (const float*)d_in[3];
    const float* b1  = (const float*)d_in[4];
    const float* g1  = (const float*)d_in[5];
    const float* bt1 = (const float*)d_in[6];
    const float* m1  = (const float*)d_in[7];
    const float* v1  = (const float*)d_in[8];
    const float* W2  = (const float*)d_in[9];
    const float* b2  = (const float*)d_in[10];
    const float* g2  = (const float*)d_in[11];
    const float* bt2 = (const float*)d_in[12];
    const float* m2  = (const float*)d_in[13];
    const float* v2  = (const float*)d_in[14];

    // workspace
    unsigned short* hb = (unsigned short*)d_ws;              // 12.8 MB
    unsigned short* xb = hb + (size_t)N_NODES * 64;          // 12.8 MB
    unsigned short* zb = xb + (size_t)N_NODES * 64;          // 12.8 MB
    int* cnt       = (int*)(zb + (size_t)N_NODES * 64);
    int* row_start = cnt + N_NODES;
    int* cursor    = row_start + N_NODES + 1;
    int* adj       = cursor + N_NODES;                       // 6.4 MB
    int* bsum      = adj + N_EDGES;
    int* boff      = bsum + NBLK_SCAN;

    float* out = (float*)d_out;

    const int EB = (N_EDGES + 255) / 256;

    const int n16 = N_NODES * 16;
    convert_kernel<<<(n16 + 255) / 256, 256, 0, stream>>>((const float4*)x, (uint2*)xb, n16);

    zero_int_kernel<<<NBLK_SCAN, 256, 0, stream>>>(cnt, N_NODES);
    hist_kernel<<<EB, 256, 0, stream>>>(ei, cnt);
    scanA_kernel<<<NBLK_SCAN, 256, 0, stream>>>(cnt, bsum);
    scanB_kernel<<<1, 512, 0, stream>>>(bsum, boff);
    scanC_kernel<<<NBLK_SCAN, 256, 0, stream>>>(cnt, boff, row_start, cursor);
    fill_kernel<<<EB, 256, 0, stream>>>(ei, cursor, adj);

    for (int l = 0; l < 4; ++l) {
        const unsigned short* hin = (l == 0) ? xb : hb;
        gather_kernel<<<GATHER_BLOCKS, 256, 0, stream>>>(hin, zb, row_start, adj);
        mlp_mfma_kernel<<<NB_MLP, 256, 0, stream>>>(
            zb, hb,
            W1 + (size_t)l * 64 * 128, b1 + l * 128, g1 + l * 128, bt1 + l * 128,
            m1 + l * 128, v1 + l * 128,
            W2 + (size_t)l * 128 * 64, b2 + l * 64, g2 + l * 64, bt2 + l * 64,
            m2 + l * 64, v2 + l * 64,
            (l != 3) ? 1 : 0);
    }

    pool_kernel<<<N_GRAPHS, 64, 0, stream>>>(hb, batch, out);
}